// Round 13
// baseline (219.262 us; speedup 1.0000x reference)
//
#include <hip/hip_runtime.h>

// HOGCN: 2-layer GraphConv, N=50000, D=64, E=1.6M, fp32.
// Round 13 = round 12 (218us) + quarter-lane aggregation:
//   lane = feature QUAD (uint2 = 4 bf16, 8B). 16 lanes cover a Z-row, so one
//   wave-gather (dwordx2, 512B) services FOUR edges. VMEM requests/edge
//   0.5 -> 0.25, epk loads/edge 0.5 -> 0.25, loop bookkeeping halves.
//   Reduction: __shfl_xor 16 + 32 (quarter bits are lane[4:5]); quarter 0
//   writes float4 (final) / uint2 bf16 (Hb). Gather BYTES unchanged
//   (128B/edge row) - the r9-r12 data shows dur tracks requests, not bytes.
// Everything else identical to round 12 (proven): padded-bucket build,
// 4B epk records, MFMA transform, bf16 Zb/Yb/Hb.

#define NN 50000
#define DD 64
#define EE 1600000
#define NPB 64                              // dst nodes per bucket
#define NB  ((NN + NPB - 1) / NPB)          // 782 buckets
#define PAD 2560                            // slots/bucket (11-sigma bound)
#define CHUNK 8192                          // edges per chunk
#define NC ((EE + CHUNK - 1) / CHUNK)       // 196 chunks

static_assert(NC <= 256, "colscan_kernel scan width must cover all chunks");
static_assert(NB <= 1024, "LDS cursor arrays sized for NB");

typedef __attribute__((ext_vector_type(8))) short short8;   // 8 bf16, 4 VGPRs
typedef __attribute__((ext_vector_type(4))) float f32x4;

__device__ __forceinline__ unsigned short f2bf(float f) {   // RNE
    unsigned u = __float_as_uint(f);
    u += 0x7FFF + ((u >> 16) & 1);
    return (unsigned short)(u >> 16);
}
__device__ __forceinline__ float bflo(unsigned u) {         // low bf16 of uint
    return __uint_as_float(u << 16);
}
__device__ __forceinline__ float bfhi(unsigned u) {         // high bf16 of uint
    return __uint_as_float(u & 0xFFFF0000u);
}

// ---------- build 1: per-chunk histogram over buckets ----------
__global__ __launch_bounds__(256) void hist_kernel(
    const int* __restrict__ ei, int* __restrict__ hist)
{
    __shared__ int lh[NB];
    const int c = blockIdx.x, t = threadIdx.x;
    for (int b = t; b < NB; b += 256) lh[b] = 0;
    __syncthreads();
    const int base = c * CHUNK;
#pragma unroll 4
    for (int i = 0; i < CHUNK; i += 256) {
        int e = base + i + t;
        if (e < EE) atomicAdd(&lh[ei[EE + e] >> 6], 1);   // dst row
    }
    __syncthreads();
    for (int b = t; b < NB; b += 256) hist[c * NB + b] = lh[b];  // coalesced
}

// ---------- build 2: per-bucket scan over chunks (782 parallel blocks) ----
__global__ __launch_bounds__(256) void colscan_kernel(
    const int* __restrict__ hist, int* __restrict__ offs, int* __restrict__ bsz)
{
    __shared__ int part[256];
    const int b = blockIdx.x, t = threadIdx.x;
    int h = (t < NC) ? hist[t * NB + b] : 0;
    part[t] = h;
    __syncthreads();
    for (int off = 1; off < 256; off <<= 1) {        // Hillis-Steele inclusive
        int v = (t >= off) ? part[t - off] : 0;
        __syncthreads();
        part[t] += v;
        __syncthreads();
    }
    if (t < NC) offs[t * NB + b] = b * PAD + (part[t] - h);   // exclusive
    if (t == 255) bsz[b] = part[255];
}

// ---------- build 3: bin edges via LDS cursors ----------
// packed.x = src | (dst&63)<<16  (src < 2^16), packed.y = fp32 weight bits.
__global__ __launch_bounds__(256) void bin_kernel(
    const int* __restrict__ ei, const float* __restrict__ ew,
    const int* __restrict__ offs, int2* __restrict__ packed)
{
    __shared__ int cur[NB];
    const int c = blockIdx.x, t = threadIdx.x;
    for (int b = t; b < NB; b += 256) cur[b] = offs[c * NB + b];
    __syncthreads();
    const int base = c * CHUNK;
    for (int i = 0; i < CHUNK; i += 256) {
        int e = base + i + t;
        if (e < EE) {
            int src = ei[e];
            int dst = ei[EE + e];
            int wb  = __float_as_int(ew[e]);
            int pos = atomicAdd(&cur[dst >> 6], 1);   // LDS atomic
            packed[pos] = make_int2(src | ((dst & 63) << 16), wb);
        }
    }
}

// ---------- build 4: per-bucket LDS counting sort ----------
// Emits 4B records: src(16b) | bf16(w)<<16. dst implicit via [beg,endo).
__global__ __launch_bounds__(256) void sort_kernel(
    const int2* __restrict__ packed, const int* __restrict__ bsz,
    unsigned* __restrict__ epk, int* __restrict__ beg, int* __restrict__ endo)
{
    __shared__ int      cnt[NPB];
    __shared__ int      cur[NPB];
    __shared__ unsigned stage[PAD];         // 10.2 KB
    const int bk = blockIdx.x, t = threadIdx.x;
    const int base = bk * PAD;
    int sz = bsz[bk];
    if (sz > PAD) sz = PAD;                 // LDS guard (unreachable)

    if (t < NPB) cnt[t] = 0;
    __syncthreads();
    for (int i = t; i < sz; i += 256)
        atomicAdd(&cnt[(packed[base + i].x >> 16) & 63], 1);
    __syncthreads();

    if (t < 64) {                           // wave 0: exclusive scan, 64 counts
        int c = cnt[t];
        int v = c;
        for (int off = 1; off < 64; off <<= 1) {
            int u = __shfl_up(v, off);
            if (t >= off) v += u;
        }
        int ex = v - c;
        cur[t] = ex;
        int g = bk * NPB + t;
        if (g < NN) { beg[g] = base + ex; endo[g] = base + ex + c; }
    }
    __syncthreads();

    for (int i = t; i < sz; i += 256) {
        int2 p = packed[base + i];
        int pos = atomicAdd(&cur[(p.x >> 16) & 63], 1);
        unsigned wu = (unsigned)p.y;
        wu += 0x7FFF + ((wu >> 16) & 1);    // RNE fp32 -> bf16
        stage[pos] = (wu & 0xFFFF0000u) | (unsigned)(p.x & 0xFFFF);
    }
    __syncthreads();
    for (int i = t; i < sz; i += 256)
        epk[base + i] = stage[i];           // sequential full-line writeback
}

// ---------- dense transforms via MFMA ----------
// Block = 64 nodes. Stage X-tile (64x64) and Wcat (128x64) as bf16 in LDS,
// rows padded to 72 shorts. TIn = float (layer 1, x) or ushort (layer 2, Hb).
#define XS_STR 72
#define WS_STR 72

template <typename TIn>
__global__ __launch_bounds__(256) void transform_kernel(
    const TIn* __restrict__ xin,
    const float* __restrict__ Wrel, const float* __restrict__ Wroot,
    const float* __restrict__ bias,
    unsigned short* __restrict__ Zb, unsigned short* __restrict__ Yb)
{
    __shared__ unsigned short Xs[64 * XS_STR];    //  9.2 KB
    __shared__ unsigned short Ws[128 * WS_STR];   // 18.4 KB

    const int t = threadIdx.x;
    const int node0 = blockIdx.x * 64;

    // stage Wcat: 2048 float4s, 8 per thread
#pragma unroll
    for (int i = 0; i < 8; ++i) {
        int flat = i * 256 + t;              // float4 index 0..2047
        int row  = flat >> 4;                // 0..127
        int c4   = flat & 15;
        const float* src = (row < 64 ? Wrel + row * 64
                                     : Wroot + (row - 64) * 64) + c4 * 4;
        float4 v = *(const float4*)src;
        unsigned short* d = &Ws[row * WS_STR + c4 * 4];
        d[0] = f2bf(v.x); d[1] = f2bf(v.y); d[2] = f2bf(v.z); d[3] = f2bf(v.w);
    }
    // stage X tile (zero-pad past NN)
    if constexpr (sizeof(TIn) == 4) {        // fp32 input
#pragma unroll
        for (int i = 0; i < 4; ++i) {
            int flat = i * 256 + t;          // 0..1023 float4s
            int row  = flat >> 4;            // 0..63
            int c4   = flat & 15;
            int node = node0 + row;
            float4 v = make_float4(0.f, 0.f, 0.f, 0.f);
            if (node < NN) v = *(const float4*)((const float*)xin + (size_t)node * 64 + c4 * 4);
            unsigned short* d = &Xs[row * XS_STR + c4 * 4];
            d[0] = f2bf(v.x); d[1] = f2bf(v.y); d[2] = f2bf(v.z); d[3] = f2bf(v.w);
        }
    } else {                                 // bf16 input (Hb)
#pragma unroll
        for (int i = 0; i < 2; ++i) {
            int flat = i * 256 + t;          // 0..511 short8s
            int row  = flat >> 3;            // 0..63
            int c8   = flat & 7;
            int node = node0 + row;
            short8 v = {0,0,0,0,0,0,0,0};
            if (node < NN)
                v = *(const short8*)((const unsigned short*)xin + (size_t)node * 64 + c8 * 8);
            *(short8*)&Xs[row * XS_STR + c8 * 8] = v;
        }
    }
    __syncthreads();

    const int w    = t >> 6;                 // wave: node rows w*16..w*16+15
    const int lane = t & 63;
    const int l15  = lane & 15;
    const int quad = lane >> 4;

    // A fragments: A[m=l15][k=quad*8+j], K-halves 0..31 / 32..63
    short8 a0 = *(const short8*)&Xs[(w * 16 + l15) * XS_STR + quad * 8];
    short8 a1 = *(const short8*)&Xs[(w * 16 + l15) * XS_STR + 32 + quad * 8];

#pragma unroll
    for (int f = 0; f < 8; ++f) {
        short8 b0 = *(const short8*)&Ws[(f * 16 + l15) * WS_STR + quad * 8];
        short8 b1 = *(const short8*)&Ws[(f * 16 + l15) * WS_STR + 32 + quad * 8];
        f32x4 acc = {0.f, 0.f, 0.f, 0.f};
        acc = __builtin_amdgcn_mfma_f32_16x16x32_bf16(a0, b0, acc, 0, 0, 0);
        acc = __builtin_amdgcn_mfma_f32_16x16x32_bf16(a1, b1, acc, 0, 0, 0);
        const int col = f * 16 + l15;        // 0..127 in [Z | Y]
#pragma unroll
        for (int r = 0; r < 4; ++r) {        // D row = quad*4 + r
            int node = node0 + w * 16 + quad * 4 + r;
            if (node < NN) {
                if (col < 64) Zb[(size_t)node * 64 + col] = f2bf(acc[r]);
                else          Yb[(size_t)node * 64 + (col - 64)] =
                                  f2bf(acc[r] + bias[col - 64]);
            }
        }
    }
}

// ---------- aggregation (fused relu epilogue), quarter lanes ----------
// Wave per dst node. s = lane&15 -> feature quad (4s..4s+3, uint2 = 8B);
// q = lane>>4 -> edge phase. One wave-gather services FOUR edges
// (8B/lane x 64 = 512B; 128B contiguous per 16-lane group).
// Reduction: __shfl_xor 16 + 32; quarter 0 writes.
template <bool FP32OUT>
__global__ __launch_bounds__(256) void aggregate_kernel(
    const uint2* __restrict__ Z4,           // Zb rows as 16 x uint2
    const uint2* __restrict__ Y4,           // Yb rows as 16 x uint2
    const int* __restrict__ beg, const int* __restrict__ endo,
    const unsigned* __restrict__ epk, void* __restrict__ Hout)
{
    const int lane = threadIdx.x & 63;
    const int node = blockIdx.x * 4 + (threadIdx.x >> 6);
    if (node >= NN) return;
    const int s = lane & 15;
    const int q = lane >> 4;

    const int b = beg[node];
    const int e = endo[node];
    const uint2 y4 = Y4[node * 16 + s];

    float a0 = 0.f, a1 = 0.f, a2 = 0.f, a3 = 0.f;
    int i = b;
    for (; i + 8 <= e; i += 8) {            // 2 quad-slots = 8 edges
        unsigned pA = epk[i + q];
        unsigned pB = epk[i + 4 + q];
        uint2 zA = Z4[(pA & 0xFFFF) * 16 + s];
        uint2 zB = Z4[(pB & 0xFFFF) * 16 + s];
        float wA = __uint_as_float(pA & 0xFFFF0000u);
        float wB = __uint_as_float(pB & 0xFFFF0000u);
        a0 = fmaf(wA, bflo(zA.x), a0);
        a1 = fmaf(wA, bfhi(zA.x), a1);
        a2 = fmaf(wA, bflo(zA.y), a2);
        a3 = fmaf(wA, bfhi(zA.y), a3);
        a0 = fmaf(wB, bflo(zB.x), a0);
        a1 = fmaf(wB, bfhi(zB.x), a1);
        a2 = fmaf(wB, bflo(zB.y), a2);
        a3 = fmaf(wB, bfhi(zB.y), a3);
    }
    for (; i < e; i += 4) {                 // tail: predicated quad-slot
        int ee = i + q;
        unsigned p = (ee < e) ? epk[ee] : 0u;   // w=+0 kills the lane
        uint2 z = Z4[(p & 0xFFFF) * 16 + s];
        float w = __uint_as_float(p & 0xFFFF0000u);
        a0 = fmaf(w, bflo(z.x), a0);
        a1 = fmaf(w, bfhi(z.x), a1);
        a2 = fmaf(w, bflo(z.y), a2);
        a3 = fmaf(w, bfhi(z.y), a3);
    }

    a0 += __shfl_xor(a0, 16); a0 += __shfl_xor(a0, 32);   // combine quarters
    a1 += __shfl_xor(a1, 16); a1 += __shfl_xor(a1, 32);
    a2 += __shfl_xor(a2, 16); a2 += __shfl_xor(a2, 32);
    a3 += __shfl_xor(a3, 16); a3 += __shfl_xor(a3, 32);

    if (q == 0) {
        float r0 = fmaxf(a0 + bflo(y4.x), 0.0f);
        float r1 = fmaxf(a1 + bfhi(y4.x), 0.0f);
        float r2 = fmaxf(a2 + bflo(y4.y), 0.0f);
        float r3 = fmaxf(a3 + bfhi(y4.y), 0.0f);
        if (FP32OUT) {
            ((float4*)Hout)[node * 16 + s] = make_float4(r0, r1, r2, r3);
        } else {
            uint2 o;
            o.x = (unsigned)f2bf(r0) | ((unsigned)f2bf(r1) << 16);
            o.y = (unsigned)f2bf(r2) | ((unsigned)f2bf(r3) << 16);
            ((uint2*)Hout)[node * 16 + s] = o;
        }
    }
}

extern "C" void kernel_launch(void* const* d_in, const int* in_sizes, int n_in,
                              void* d_out, int out_size, void* d_ws, size_t ws_size,
                              hipStream_t stream)
{
    const float* x     = (const float*)d_in[0];
    const int*   ei    = (const int*)  d_in[1];
    const float* ew    = (const float*)d_in[2];
    const float* Wrel1 = (const float*)d_in[3];
    const float* brel1 = (const float*)d_in[4];
    const float* Wroot1= (const float*)d_in[5];
    const float* Wrel2 = (const float*)d_in[6];
    const float* brel2 = (const float*)d_in[7];
    const float* Wroot2= (const float*)d_in[8];

    float* out = (float*)d_out;                 // final output only

    const size_t ND = (size_t)NN * DD;          // 3.2e6 elements
    // ALL regions disjoint. Total ~44.9 MB (ws = 256 MiB).
    char* w = (char*)d_ws;
    unsigned short* Zb = (unsigned short*)w;                    //  6.40 MB
    unsigned short* Yb = (unsigned short*)(w + ND * 2);         //  6.40 MB
    unsigned short* Hb = (unsigned short*)(w + ND * 4);         //  6.40 MB
    int2*  packed = (int2*)(w + ND * 6);                        // 16.02 MB
    unsigned* epk = (unsigned*)(w + ND * 6 + (size_t)NB * PAD * 8); // 8.01 MB
    int* beg  = (int*)(w + ND * 6 + (size_t)NB * PAD * 12);     //  0.20 MB
    int* endo = beg + NN;                                       //  0.20 MB
    int* bsz  = endo + NN;                                      //  3 KB
    int* hist = bsz + NB;                                       //  0.61 MB
    int* offs = hist + (size_t)NC * NB;                         //  0.61 MB

    // ---- build exact per-node grouping (shared by both layers) ----
    hist_kernel   <<<NC, 256, 0, stream>>>(ei, hist);
    colscan_kernel<<<NB, 256, 0, stream>>>(hist, offs, bsz);
    bin_kernel    <<<NC, 256, 0, stream>>>(ei, ew, offs, packed);
    sort_kernel   <<<NB, 256, 0, stream>>>(packed, bsz, epk, beg, endo);

    const int tb = (NN + 63) / 64;              // 782 transform blocks
    const int ab = (NN + 3) / 4;                // 12500 aggregate blocks

    // ---- layer 1 ----
    transform_kernel<float><<<tb, 256, 0, stream>>>(x, Wrel1, Wroot1, brel1, Zb, Yb);
    aggregate_kernel<false><<<ab, 256, 0, stream>>>(
        (const uint2*)Zb, (const uint2*)Yb, beg, endo, epk, Hb);

    // ---- layer 2 ----
    transform_kernel<unsigned short><<<tb, 256, 0, stream>>>(Hb, Wrel2, Wroot2, brel2, Zb, Yb);
    aggregate_kernel<true><<<ab, 256, 0, stream>>>(
        (const uint2*)Zb, (const uint2*)Yb, beg, endo, epk, out);
}

// Round 14
// 209.481 us; speedup vs baseline: 1.0467x; 1.0467x over previous
//
#include <hip/hip_runtime.h>

// HOGCN: 2-layer GraphConv, N=50000, D=64, E=1.6M, fp32.
// Round 14 = round 13 (219us) + mid-tier cuts:
//  (a) hist + layer-1 transform FUSED into one launch (disjoint in/out,
//      block-range split) - they co-schedule instead of serializing.
//  (b) bin emits 4B records src(16)|dst6(6)|w10(10) (w as 10-bit fixed
//      point, abs err <= 5e-4 -> output err ~0.016). Bin write traffic
//      halves; sort is IN-PLACE on the single 4B buffer and expands
//      w10 -> bf16 once per edge (aggregate format unchanged).
//  (c) aggregate main loop deepened to 16 edges (4 row-gathers in flight).
// r13 lesson: aggregate is at a latency/L1-miss-path equilibrium (~5.9TB/s
// effective on random 128B rows); request cuts are neutral there. This
// round targets the unmeasured build/transform/serialization middle.

#define NN 50000
#define DD 64
#define EE 1600000
#define NPB 64                              // dst nodes per bucket
#define NB  ((NN + NPB - 1) / NPB)          // 782 buckets
#define PAD 2560                            // slots/bucket (11-sigma bound)
#define CHUNK 8192                          // edges per chunk
#define NC ((EE + CHUNK - 1) / CHUNK)       // 196 chunks

static_assert(NC <= 256, "colscan_kernel scan width must cover all chunks");
static_assert(NB <= 1024, "LDS cursor arrays sized for NB");

typedef __attribute__((ext_vector_type(8))) short short8;   // 8 bf16, 4 VGPRs
typedef __attribute__((ext_vector_type(4))) float f32x4;

__device__ __forceinline__ unsigned short f2bf(float f) {   // RNE
    unsigned u = __float_as_uint(f);
    u += 0x7FFF + ((u >> 16) & 1);
    return (unsigned short)(u >> 16);
}
__device__ __forceinline__ float bflo(unsigned u) {
    return __uint_as_float(u << 16);
}
__device__ __forceinline__ float bfhi(unsigned u) {
    return __uint_as_float(u & 0xFFFF0000u);
}

#define XS_STR 72
#define WS_STR 72

// ---------- dense transform body (MFMA), shared by both layers ----------
// Xs/Ws staged by caller-side code below; see round-10 provenance for the
// HW-verified fragment layouts.
template <typename TIn>
__device__ __forceinline__ void transform_body(
    int blk, int t,
    const TIn* __restrict__ xin,
    const float* __restrict__ Wrel, const float* __restrict__ Wroot,
    const float* __restrict__ bias,
    unsigned short* __restrict__ Zb, unsigned short* __restrict__ Yb,
    unsigned short* Xs, unsigned short* Ws)
{
    const int node0 = blk * 64;

    // stage Wcat: 2048 float4s, 8 per thread
#pragma unroll
    for (int i = 0; i < 8; ++i) {
        int flat = i * 256 + t;              // float4 index 0..2047
        int row  = flat >> 4;                // 0..127
        int c4   = flat & 15;
        const float* src = (row < 64 ? Wrel + row * 64
                                     : Wroot + (row - 64) * 64) + c4 * 4;
        float4 v = *(const float4*)src;
        unsigned short* d = &Ws[row * WS_STR + c4 * 4];
        d[0] = f2bf(v.x); d[1] = f2bf(v.y); d[2] = f2bf(v.z); d[3] = f2bf(v.w);
    }
    // stage X tile (zero-pad past NN)
    if constexpr (sizeof(TIn) == 4) {        // fp32 input
#pragma unroll
        for (int i = 0; i < 4; ++i) {
            int flat = i * 256 + t;          // 0..1023 float4s
            int row  = flat >> 4;
            int c4   = flat & 15;
            int node = node0 + row;
            float4 v = make_float4(0.f, 0.f, 0.f, 0.f);
            if (node < NN) v = *(const float4*)((const float*)xin + (size_t)node * 64 + c4 * 4);
            unsigned short* d = &Xs[row * XS_STR + c4 * 4];
            d[0] = f2bf(v.x); d[1] = f2bf(v.y); d[2] = f2bf(v.z); d[3] = f2bf(v.w);
        }
    } else {                                 // bf16 input (Hb)
#pragma unroll
        for (int i = 0; i < 2; ++i) {
            int flat = i * 256 + t;          // 0..511 short8s
            int row  = flat >> 3;
            int c8   = flat & 7;
            int node = node0 + row;
            short8 v = {0,0,0,0,0,0,0,0};
            if (node < NN)
                v = *(const short8*)((const unsigned short*)xin + (size_t)node * 64 + c8 * 8);
            *(short8*)&Xs[row * XS_STR + c8 * 8] = v;
        }
    }
    __syncthreads();

    const int w    = t >> 6;                 // wave: node rows w*16..w*16+15
    const int lane = t & 63;
    const int l15  = lane & 15;
    const int quad = lane >> 4;

    short8 a0 = *(const short8*)&Xs[(w * 16 + l15) * XS_STR + quad * 8];
    short8 a1 = *(const short8*)&Xs[(w * 16 + l15) * XS_STR + 32 + quad * 8];

#pragma unroll
    for (int f = 0; f < 8; ++f) {
        short8 b0 = *(const short8*)&Ws[(f * 16 + l15) * WS_STR + quad * 8];
        short8 b1 = *(const short8*)&Ws[(f * 16 + l15) * WS_STR + 32 + quad * 8];
        f32x4 acc = {0.f, 0.f, 0.f, 0.f};
        acc = __builtin_amdgcn_mfma_f32_16x16x32_bf16(a0, b0, acc, 0, 0, 0);
        acc = __builtin_amdgcn_mfma_f32_16x16x32_bf16(a1, b1, acc, 0, 0, 0);
        const int col = f * 16 + l15;        // 0..127 in [Z | Y]
#pragma unroll
        for (int r = 0; r < 4; ++r) {        // D row = quad*4 + r
            int node = node0 + w * 16 + quad * 4 + r;
            if (node < NN) {
                if (col < 64) Zb[(size_t)node * 64 + col] = f2bf(acc[r]);
                else          Yb[(size_t)node * 64 + (col - 64)] =
                                  f2bf(acc[r] + bias[col - 64]);
            }
        }
    }
}

// ---------- fused: hist (blocks 0..NC-1) + layer-1 transform (rest) -----
__global__ __launch_bounds__(256) void hist_t1_kernel(
    const int* __restrict__ ei, int* __restrict__ hist,
    const float* __restrict__ x,
    const float* __restrict__ Wrel, const float* __restrict__ Wroot,
    const float* __restrict__ bias,
    unsigned short* __restrict__ Zb, unsigned short* __restrict__ Yb)
{
    __shared__ int lh[NB];                        //  3.1 KB
    __shared__ unsigned short Xs[64 * XS_STR];    //  9.2 KB
    __shared__ unsigned short Ws[128 * WS_STR];   // 18.4 KB
    const int t = threadIdx.x;

    if (blockIdx.x < NC) {                   // ---- histogram chunk ----
        const int c = blockIdx.x;
        for (int b = t; b < NB; b += 256) lh[b] = 0;
        __syncthreads();
        const int base = c * CHUNK;
#pragma unroll 4
        for (int i = 0; i < CHUNK; i += 256) {
            int e = base + i + t;
            if (e < EE) atomicAdd(&lh[ei[EE + e] >> 6], 1);   // dst row
        }
        __syncthreads();
        for (int b = t; b < NB; b += 256) hist[c * NB + b] = lh[b];
    } else {                                 // ---- layer-1 transform ----
        transform_body<float>(blockIdx.x - NC, t, x, Wrel, Wroot, bias,
                              Zb, Yb, Xs, Ws);
    }
}

// ---------- layer-2 transform (bf16 input) ----------
__global__ __launch_bounds__(256) void transform2_kernel(
    const unsigned short* __restrict__ xin,
    const float* __restrict__ Wrel, const float* __restrict__ Wroot,
    const float* __restrict__ bias,
    unsigned short* __restrict__ Zb, unsigned short* __restrict__ Yb)
{
    __shared__ unsigned short Xs[64 * XS_STR];
    __shared__ unsigned short Ws[128 * WS_STR];
    transform_body<unsigned short>(blockIdx.x, threadIdx.x, xin, Wrel, Wroot,
                                   bias, Zb, Yb, Xs, Ws);
}

// ---------- build 2: per-bucket scan over chunks (782 parallel blocks) ----
__global__ __launch_bounds__(256) void colscan_kernel(
    const int* __restrict__ hist, int* __restrict__ offs, int* __restrict__ bsz)
{
    __shared__ int part[256];
    const int b = blockIdx.x, t = threadIdx.x;
    int h = (t < NC) ? hist[t * NB + b] : 0;
    part[t] = h;
    __syncthreads();
    for (int off = 1; off < 256; off <<= 1) {        // Hillis-Steele inclusive
        int v = (t >= off) ? part[t - off] : 0;
        __syncthreads();
        part[t] += v;
        __syncthreads();
    }
    if (t < NC) offs[t * NB + b] = b * PAD + (part[t] - h);   // exclusive
    if (t == 255) bsz[b] = part[255];
}

// ---------- build 3: bin edges via LDS cursors, 4B records ----------
// record = src(16) | (dst&63)<<16 | q<<22, q = round(w*1023) in [0,1023].
__global__ __launch_bounds__(256) void bin_kernel(
    const int* __restrict__ ei, const float* __restrict__ ew,
    const int* __restrict__ offs, unsigned* __restrict__ epk)
{
    __shared__ int cur[NB];
    const int c = blockIdx.x, t = threadIdx.x;
    for (int b = t; b < NB; b += 256) cur[b] = offs[c * NB + b];
    __syncthreads();
    const int base = c * CHUNK;
    for (int i = 0; i < CHUNK; i += 256) {
        int e = base + i + t;
        if (e < EE) {
            int src = ei[e];
            int dst = ei[EE + e];
            unsigned q = (unsigned)fmaf(ew[e], 1023.0f, 0.5f);  // 0..1023
            int pos = atomicAdd(&cur[dst >> 6], 1);   // LDS atomic
            epk[pos] = (unsigned)src | ((unsigned)(dst & 63) << 16) | (q << 22);
        }
    }
}

// ---------- build 4: per-bucket LDS counting sort (IN PLACE, 4B) ----------
// Output record: src(16) | bf16(q/1023)<<16. dst implicit via [beg,endo).
__global__ __launch_bounds__(256) void sort_kernel(
    unsigned* __restrict__ epk, const int* __restrict__ bsz,
    int* __restrict__ beg, int* __restrict__ endo)
{
    __shared__ int      cnt[NPB];
    __shared__ int      cur[NPB];
    __shared__ unsigned stage[PAD];         // 10.2 KB
    const int bk = blockIdx.x, t = threadIdx.x;
    const int base = bk * PAD;
    int sz = bsz[bk];
    if (sz > PAD) sz = PAD;                 // LDS guard (unreachable)

    if (t < NPB) cnt[t] = 0;
    __syncthreads();
    for (int i = t; i < sz; i += 256)
        atomicAdd(&cnt[(epk[base + i] >> 16) & 63], 1);
    __syncthreads();

    if (t < 64) {                           // wave 0: exclusive scan, 64 counts
        int c = cnt[t];
        int v = c;
        for (int off = 1; off < 64; off <<= 1) {
            int u = __shfl_up(v, off);
            if (t >= off) v += u;
        }
        int ex = v - c;
        cur[t] = ex;
        int g = bk * NPB + t;
        if (g < NN) { beg[g] = base + ex; endo[g] = base + ex + c; }
    }
    __syncthreads();

    for (int i = t; i < sz; i += 256) {
        unsigned p = epk[base + i];
        int pos = atomicAdd(&cur[(p >> 16) & 63], 1);
        float w = (float)(p >> 22) * (1.0f / 1023.0f);
        stage[pos] = (p & 0xFFFFu) | ((unsigned)f2bf(w) << 16);
    }
    __syncthreads();
    for (int i = t; i < sz; i += 256)
        epk[base + i] = stage[i];           // in-place, sequential full lines
}

// ---------- aggregation (fused relu epilogue), quarter lanes ----------
// Wave per dst node. s = lane&15 -> feature quad (uint2 = 4 bf16, 8B);
// q = lane>>4 -> edge phase. Main loop: 16 edges, 4 row-gathers in flight.
template <bool FP32OUT>
__global__ __launch_bounds__(256) void aggregate_kernel(
    const uint2* __restrict__ Z4, const uint2* __restrict__ Y4,
    const int* __restrict__ beg, const int* __restrict__ endo,
    const unsigned* __restrict__ epk, void* __restrict__ Hout)
{
    const int lane = threadIdx.x & 63;
    const int node = blockIdx.x * 4 + (threadIdx.x >> 6);
    if (node >= NN) return;
    const int s = lane & 15;
    const int q = lane >> 4;

    const int b = beg[node];
    const int e = endo[node];
    const uint2 y4 = Y4[node * 16 + s];

    float a0 = 0.f, a1 = 0.f, a2 = 0.f, a3 = 0.f;
    int i = b;
    for (; i + 16 <= e; i += 16) {          // 4 quad-slots = 16 edges
        unsigned pA = epk[i + q];
        unsigned pB = epk[i + 4 + q];
        unsigned pC = epk[i + 8 + q];
        unsigned pD = epk[i + 12 + q];
        uint2 zA = Z4[(pA & 0xFFFF) * 16 + s];
        uint2 zB = Z4[(pB & 0xFFFF) * 16 + s];
        uint2 zC = Z4[(pC & 0xFFFF) * 16 + s];
        uint2 zD = Z4[(pD & 0xFFFF) * 16 + s];
        float wA = __uint_as_float(pA & 0xFFFF0000u);
        float wB = __uint_as_float(pB & 0xFFFF0000u);
        float wC = __uint_as_float(pC & 0xFFFF0000u);
        float wD = __uint_as_float(pD & 0xFFFF0000u);
        a0 = fmaf(wA, bflo(zA.x), a0); a1 = fmaf(wA, bfhi(zA.x), a1);
        a2 = fmaf(wA, bflo(zA.y), a2); a3 = fmaf(wA, bfhi(zA.y), a3);
        a0 = fmaf(wB, bflo(zB.x), a0); a1 = fmaf(wB, bfhi(zB.x), a1);
        a2 = fmaf(wB, bflo(zB.y), a2); a3 = fmaf(wB, bfhi(zB.y), a3);
        a0 = fmaf(wC, bflo(zC.x), a0); a1 = fmaf(wC, bfhi(zC.x), a1);
        a2 = fmaf(wC, bflo(zC.y), a2); a3 = fmaf(wC, bfhi(zC.y), a3);
        a0 = fmaf(wD, bflo(zD.x), a0); a1 = fmaf(wD, bfhi(zD.x), a1);
        a2 = fmaf(wD, bflo(zD.y), a2); a3 = fmaf(wD, bfhi(zD.y), a3);
    }
    for (; i < e; i += 4) {                 // tail: predicated quad-slot
        int ee = i + q;
        unsigned p = (ee < e) ? epk[ee] : 0u;   // w=+0 kills the lane
        uint2 z = Z4[(p & 0xFFFF) * 16 + s];
        float w = __uint_as_float(p & 0xFFFF0000u);
        a0 = fmaf(w, bflo(z.x), a0); a1 = fmaf(w, bfhi(z.x), a1);
        a2 = fmaf(w, bflo(z.y), a2); a3 = fmaf(w, bfhi(z.y), a3);
    }

    a0 += __shfl_xor(a0, 16); a0 += __shfl_xor(a0, 32);
    a1 += __shfl_xor(a1, 16); a1 += __shfl_xor(a1, 32);
    a2 += __shfl_xor(a2, 16); a2 += __shfl_xor(a2, 32);
    a3 += __shfl_xor(a3, 16); a3 += __shfl_xor(a3, 32);

    if (q == 0) {
        float r0 = fmaxf(a0 + bflo(y4.x), 0.0f);
        float r1 = fmaxf(a1 + bfhi(y4.x), 0.0f);
        float r2 = fmaxf(a2 + bflo(y4.y), 0.0f);
        float r3 = fmaxf(a3 + bfhi(y4.y), 0.0f);
        if (FP32OUT) {
            ((float4*)Hout)[node * 16 + s] = make_float4(r0, r1, r2, r3);
        } else {
            uint2 o;
            o.x = (unsigned)f2bf(r0) | ((unsigned)f2bf(r1) << 16);
            o.y = (unsigned)f2bf(r2) | ((unsigned)f2bf(r3) << 16);
            ((uint2*)Hout)[node * 16 + s] = o;
        }
    }
}

extern "C" void kernel_launch(void* const* d_in, const int* in_sizes, int n_in,
                              void* d_out, int out_size, void* d_ws, size_t ws_size,
                              hipStream_t stream)
{
    const float* x     = (const float*)d_in[0];
    const int*   ei    = (const int*)  d_in[1];
    const float* ew    = (const float*)d_in[2];
    const float* Wrel1 = (const float*)d_in[3];
    const float* brel1 = (const float*)d_in[4];
    const float* Wroot1= (const float*)d_in[5];
    const float* Wrel2 = (const float*)d_in[6];
    const float* brel2 = (const float*)d_in[7];
    const float* Wroot2= (const float*)d_in[8];

    float* out = (float*)d_out;                 // final output only

    const size_t ND = (size_t)NN * DD;          // 3.2e6 elements
    // ALL regions disjoint. Total ~29.5 MB (ws = 256 MiB).
    char* w = (char*)d_ws;
    unsigned short* Zb = (unsigned short*)w;                    //  6.40 MB
    unsigned short* Yb = (unsigned short*)(w + ND * 2);         //  6.40 MB
    unsigned short* Hb = (unsigned short*)(w + ND * 4);         //  6.40 MB
    unsigned* epk = (unsigned*)(w + ND * 6);                    //  8.01 MB
    int* beg  = (int*)(w + ND * 6 + (size_t)NB * PAD * 4);      //  0.20 MB
    int* endo = beg + NN;                                       //  0.20 MB
    int* bsz  = endo + NN;                                      //  3 KB
    int* hist = bsz + NB;                                       //  0.61 MB
    int* offs = hist + (size_t)NC * NB;                         //  0.61 MB

    const int tb = (NN + 63) / 64;              // 782 transform blocks
    const int ab = (NN + 3) / 4;                // 12500 aggregate blocks

    // ---- fused: histogram chunks + layer-1 transform (independent) ----
    hist_t1_kernel<<<NC + tb, 256, 0, stream>>>(ei, hist, x, Wrel1, Wroot1,
                                                brel1, Zb, Yb);
    // ---- rest of the build (graph shared by both layers) ----
    colscan_kernel<<<NB, 256, 0, stream>>>(hist, offs, bsz);
    bin_kernel    <<<NC, 256, 0, stream>>>(ei, ew, offs, epk);
    sort_kernel   <<<NB, 256, 0, stream>>>(epk, bsz, beg, endo);

    // ---- layer 1 aggregate ----
    aggregate_kernel<false><<<ab, 256, 0, stream>>>(
        (const uint2*)Zb, (const uint2*)Yb, beg, endo, epk, Hb);

    // ---- layer 2 ----
    transform2_kernel<<<tb, 256, 0, stream>>>(Hb, Wrel2, Wroot2, brel2, Zb, Yb);
    aggregate_kernel<true><<<ab, 256, 0, stream>>>(
        (const uint2*)Zb, (const uint2*)Yb, beg, endo, epk, out);
}

// Round 15
// 189.882 us; speedup vs baseline: 1.1547x; 1.1032x over previous
//
#include <hip/hip_runtime.h>

// HOGCN: 2-layer GraphConv, N=50000, D=64, E=1.6M, fp32.
// Round 15 = round 14 (209us) + ONE change: Z stored as fp8 e4m3.
//   A Z row becomes 64B = ONE cache line (bf16 was 128B = 2 lines).
//   r12-r14 evidence: aggregate is bound by divergent-LINE processing
//   (~42cyc/VMEM-inst; request cuts neutral, byte cuts helped) -> halving
//   lines/edge is the lever. Bonus: Z = 3.2MB fits per-XCD 4MB L2 entirely.
//   Error budget: sigma_z~0.6, e4m3 rel ~3%, 32-sum x 2 layers -> adds
//   ~0.2-0.35 absmax on top of 0.25; threshold 0.91.
// Weights(bf16-in-epk)/Yb/Hb unchanged. Build + transforms = round 14.

#define NN 50000
#define DD 64
#define EE 1600000
#define NPB 64                              // dst nodes per bucket
#define NB  ((NN + NPB - 1) / NPB)          // 782 buckets
#define PAD 2560                            // slots/bucket (11-sigma bound)
#define CHUNK 8192                          // edges per chunk
#define NC ((EE + CHUNK - 1) / CHUNK)       // 196 chunks

static_assert(NC <= 256, "colscan_kernel scan width must cover all chunks");
static_assert(NB <= 1024, "LDS cursor arrays sized for NB");

typedef __attribute__((ext_vector_type(8))) short short8;   // 8 bf16, 4 VGPRs
typedef __attribute__((ext_vector_type(4))) float f32x4;

__device__ __forceinline__ unsigned short f2bf(float f) {   // RNE
    unsigned u = __float_as_uint(f);
    u += 0x7FFF + ((u >> 16) & 1);
    return (unsigned short)(u >> 16);
}
__device__ __forceinline__ float bflo(unsigned u) {
    return __uint_as_float(u << 16);
}
__device__ __forceinline__ float bfhi(unsigned u) {
    return __uint_as_float(u & 0xFFFF0000u);
}
__device__ __forceinline__ unsigned char f2fp8(float f) {   // e4m3, RNE
    unsigned p = __builtin_amdgcn_cvt_pk_fp8_f32(f, f, 0, false);
    return (unsigned char)(p & 0xFF);
}

// ---------- dense transform body (MFMA), shared by both layers ----------
#define XS_STR 72
#define WS_STR 72

template <typename TIn>
__device__ __forceinline__ void transform_body(
    int blk, int t,
    const TIn* __restrict__ xin,
    const float* __restrict__ Wrel, const float* __restrict__ Wroot,
    const float* __restrict__ bias,
    unsigned char* __restrict__ Z8, unsigned short* __restrict__ Yb,
    unsigned short* Xs, unsigned short* Ws)
{
    const int node0 = blk * 64;

    // stage Wcat: 2048 float4s, 8 per thread
#pragma unroll
    for (int i = 0; i < 8; ++i) {
        int flat = i * 256 + t;              // float4 index 0..2047
        int row  = flat >> 4;                // 0..127
        int c4   = flat & 15;
        const float* src = (row < 64 ? Wrel + row * 64
                                     : Wroot + (row - 64) * 64) + c4 * 4;
        float4 v = *(const float4*)src;
        unsigned short* d = &Ws[row * WS_STR + c4 * 4];
        d[0] = f2bf(v.x); d[1] = f2bf(v.y); d[2] = f2bf(v.z); d[3] = f2bf(v.w);
    }
    // stage X tile (zero-pad past NN)
    if constexpr (sizeof(TIn) == 4) {        // fp32 input
#pragma unroll
        for (int i = 0; i < 4; ++i) {
            int flat = i * 256 + t;          // 0..1023 float4s
            int row  = flat >> 4;
            int c4   = flat & 15;
            int node = node0 + row;
            float4 v = make_float4(0.f, 0.f, 0.f, 0.f);
            if (node < NN) v = *(const float4*)((const float*)xin + (size_t)node * 64 + c4 * 4);
            unsigned short* d = &Xs[row * XS_STR + c4 * 4];
            d[0] = f2bf(v.x); d[1] = f2bf(v.y); d[2] = f2bf(v.z); d[3] = f2bf(v.w);
        }
    } else {                                 // bf16 input (Hb)
#pragma unroll
        for (int i = 0; i < 2; ++i) {
            int flat = i * 256 + t;          // 0..511 short8s
            int row  = flat >> 3;
            int c8   = flat & 7;
            int node = node0 + row;
            short8 v = {0,0,0,0,0,0,0,0};
            if (node < NN)
                v = *(const short8*)((const unsigned short*)xin + (size_t)node * 64 + c8 * 8);
            *(short8*)&Xs[row * XS_STR + c8 * 8] = v;
        }
    }
    __syncthreads();

    const int w    = t >> 6;                 // wave: node rows w*16..w*16+15
    const int lane = t & 63;
    const int l15  = lane & 15;
    const int quad = lane >> 4;

    short8 a0 = *(const short8*)&Xs[(w * 16 + l15) * XS_STR + quad * 8];
    short8 a1 = *(const short8*)&Xs[(w * 16 + l15) * XS_STR + 32 + quad * 8];

#pragma unroll
    for (int f = 0; f < 8; ++f) {
        short8 b0 = *(const short8*)&Ws[(f * 16 + l15) * WS_STR + quad * 8];
        short8 b1 = *(const short8*)&Ws[(f * 16 + l15) * WS_STR + 32 + quad * 8];
        f32x4 acc = {0.f, 0.f, 0.f, 0.f};
        acc = __builtin_amdgcn_mfma_f32_16x16x32_bf16(a0, b0, acc, 0, 0, 0);
        acc = __builtin_amdgcn_mfma_f32_16x16x32_bf16(a1, b1, acc, 0, 0, 0);
        const int col = f * 16 + l15;        // 0..127 in [Z | Y]
#pragma unroll
        for (int r = 0; r < 4; ++r) {        // D row = quad*4 + r
            int node = node0 + w * 16 + quad * 4 + r;
            if (node < NN) {
                if (col < 64) Z8[(size_t)node * 64 + col] = f2fp8(acc[r]);
                else          Yb[(size_t)node * 64 + (col - 64)] =
                                  f2bf(acc[r] + bias[col - 64]);
            }
        }
    }
}

// ---------- fused: hist (blocks 0..NC-1) + layer-1 transform (rest) -----
__global__ __launch_bounds__(256) void hist_t1_kernel(
    const int* __restrict__ ei, int* __restrict__ hist,
    const float* __restrict__ x,
    const float* __restrict__ Wrel, const float* __restrict__ Wroot,
    const float* __restrict__ bias,
    unsigned char* __restrict__ Z8, unsigned short* __restrict__ Yb)
{
    __shared__ int lh[NB];                        //  3.1 KB
    __shared__ unsigned short Xs[64 * XS_STR];    //  9.2 KB
    __shared__ unsigned short Ws[128 * WS_STR];   // 18.4 KB
    const int t = threadIdx.x;

    if (blockIdx.x < NC) {                   // ---- histogram chunk ----
        const int c = blockIdx.x;
        for (int b = t; b < NB; b += 256) lh[b] = 0;
        __syncthreads();
        const int base = c * CHUNK;
#pragma unroll 4
        for (int i = 0; i < CHUNK; i += 256) {
            int e = base + i + t;
            if (e < EE) atomicAdd(&lh[ei[EE + e] >> 6], 1);   // dst row
        }
        __syncthreads();
        for (int b = t; b < NB; b += 256) hist[c * NB + b] = lh[b];
    } else {                                 // ---- layer-1 transform ----
        transform_body<float>(blockIdx.x - NC, t, x, Wrel, Wroot, bias,
                              Z8, Yb, Xs, Ws);
    }
}

// ---------- layer-2 transform (bf16 input) ----------
__global__ __launch_bounds__(256) void transform2_kernel(
    const unsigned short* __restrict__ xin,
    const float* __restrict__ Wrel, const float* __restrict__ Wroot,
    const float* __restrict__ bias,
    unsigned char* __restrict__ Z8, unsigned short* __restrict__ Yb)
{
    __shared__ unsigned short Xs[64 * XS_STR];
    __shared__ unsigned short Ws[128 * WS_STR];
    transform_body<unsigned short>(blockIdx.x, threadIdx.x, xin, Wrel, Wroot,
                                   bias, Z8, Yb, Xs, Ws);
}

// ---------- build 2: per-bucket scan over chunks (782 parallel blocks) ----
__global__ __launch_bounds__(256) void colscan_kernel(
    const int* __restrict__ hist, int* __restrict__ offs, int* __restrict__ bsz)
{
    __shared__ int part[256];
    const int b = blockIdx.x, t = threadIdx.x;
    int h = (t < NC) ? hist[t * NB + b] : 0;
    part[t] = h;
    __syncthreads();
    for (int off = 1; off < 256; off <<= 1) {        // Hillis-Steele inclusive
        int v = (t >= off) ? part[t - off] : 0;
        __syncthreads();
        part[t] += v;
        __syncthreads();
    }
    if (t < NC) offs[t * NB + b] = b * PAD + (part[t] - h);   // exclusive
    if (t == 255) bsz[b] = part[255];
}

// ---------- build 3: bin edges via LDS cursors, 4B records ----------
// record = src(16) | (dst&63)<<16 | q<<22, q = round(w*1023) in [0,1023].
__global__ __launch_bounds__(256) void bin_kernel(
    const int* __restrict__ ei, const float* __restrict__ ew,
    const int* __restrict__ offs, unsigned* __restrict__ epk)
{
    __shared__ int cur[NB];
    const int c = blockIdx.x, t = threadIdx.x;
    for (int b = t; b < NB; b += 256) cur[b] = offs[c * NB + b];
    __syncthreads();
    const int base = c * CHUNK;
    for (int i = 0; i < CHUNK; i += 256) {
        int e = base + i + t;
        if (e < EE) {
            int src = ei[e];
            int dst = ei[EE + e];
            unsigned q = (unsigned)fmaf(ew[e], 1023.0f, 0.5f);  // 0..1023
            int pos = atomicAdd(&cur[dst >> 6], 1);   // LDS atomic
            epk[pos] = (unsigned)src | ((unsigned)(dst & 63) << 16) | (q << 22);
        }
    }
}

// ---------- build 4: per-bucket LDS counting sort (IN PLACE, 4B) ----------
// Output record: src(16) | bf16(q/1023)<<16. dst implicit via [beg,endo).
__global__ __launch_bounds__(256) void sort_kernel(
    unsigned* __restrict__ epk, const int* __restrict__ bsz,
    int* __restrict__ beg, int* __restrict__ endo)
{
    __shared__ int      cnt[NPB];
    __shared__ int      cur[NPB];
    __shared__ unsigned stage[PAD];         // 10.2 KB
    const int bk = blockIdx.x, t = threadIdx.x;
    const int base = bk * PAD;
    int sz = bsz[bk];
    if (sz > PAD) sz = PAD;                 // LDS guard (unreachable)

    if (t < NPB) cnt[t] = 0;
    __syncthreads();
    for (int i = t; i < sz; i += 256)
        atomicAdd(&cnt[(epk[base + i] >> 16) & 63], 1);
    __syncthreads();

    if (t < 64) {                           // wave 0: exclusive scan, 64 counts
        int c = cnt[t];
        int v = c;
        for (int off = 1; off < 64; off <<= 1) {
            int u = __shfl_up(v, off);
            if (t >= off) v += u;
        }
        int ex = v - c;
        cur[t] = ex;
        int g = bk * NPB + t;
        if (g < NN) { beg[g] = base + ex; endo[g] = base + ex + c; }
    }
    __syncthreads();

    for (int i = t; i < sz; i += 256) {
        unsigned p = epk[base + i];
        int pos = atomicAdd(&cur[(p >> 16) & 63], 1);
        float w = (float)(p >> 22) * (1.0f / 1023.0f);
        stage[pos] = (p & 0xFFFFu) | ((unsigned)f2bf(w) << 16);
    }
    __syncthreads();
    for (int i = t; i < sz; i += 256)
        epk[base + i] = stage[i];           // in-place, sequential full lines
}

// ---------- aggregation (fused relu epilogue), quarter lanes, fp8 Z ------
// Wave per dst node. s = lane&15 -> feature quad (4 fp8 = uint, 4B);
// q = lane>>4 -> edge phase. One Z row = 64B = ONE cache line.
template <bool FP32OUT>
__global__ __launch_bounds__(256) void aggregate_kernel(
    const unsigned* __restrict__ Z1,        // Z8 rows as 16 x uint
    const uint2* __restrict__ Y4,           // Yb rows as 16 x uint2
    const int* __restrict__ beg, const int* __restrict__ endo,
    const unsigned* __restrict__ epk, void* __restrict__ Hout)
{
    const int lane = threadIdx.x & 63;
    const int node = blockIdx.x * 4 + (threadIdx.x >> 6);
    if (node >= NN) return;
    const int s = lane & 15;
    const int q = lane >> 4;

    const int b = beg[node];
    const int e = endo[node];
    const uint2 y4 = Y4[node * 16 + s];

    float a0 = 0.f, a1 = 0.f, a2 = 0.f, a3 = 0.f;
    int i = b;
    for (; i + 16 <= e; i += 16) {          // 4 quad-slots = 16 edges
        unsigned pA = epk[i + q];
        unsigned pB = epk[i + 4 + q];
        unsigned pC = epk[i + 8 + q];
        unsigned pD = epk[i + 12 + q];
        unsigned zA = Z1[(pA & 0xFFFF) * 16 + s];
        unsigned zB = Z1[(pB & 0xFFFF) * 16 + s];
        unsigned zC = Z1[(pC & 0xFFFF) * 16 + s];
        unsigned zD = Z1[(pD & 0xFFFF) * 16 + s];
        float wA = __uint_as_float(pA & 0xFFFF0000u);
        float wB = __uint_as_float(pB & 0xFFFF0000u);
        float wC = __uint_as_float(pC & 0xFFFF0000u);
        float wD = __uint_as_float(pD & 0xFFFF0000u);
        a0 = fmaf(wA, __builtin_amdgcn_cvt_f32_fp8(zA, 0), a0);
        a1 = fmaf(wA, __builtin_amdgcn_cvt_f32_fp8(zA, 1), a1);
        a2 = fmaf(wA, __builtin_amdgcn_cvt_f32_fp8(zA, 2), a2);
        a3 = fmaf(wA, __builtin_amdgcn_cvt_f32_fp8(zA, 3), a3);
        a0 = fmaf(wB, __builtin_amdgcn_cvt_f32_fp8(zB, 0), a0);
        a1 = fmaf(wB, __builtin_amdgcn_cvt_f32_fp8(zB, 1), a1);
        a2 = fmaf(wB, __builtin_amdgcn_cvt_f32_fp8(zB, 2), a2);
        a3 = fmaf(wB, __builtin_amdgcn_cvt_f32_fp8(zB, 3), a3);
        a0 = fmaf(wC, __builtin_amdgcn_cvt_f32_fp8(zC, 0), a0);
        a1 = fmaf(wC, __builtin_amdgcn_cvt_f32_fp8(zC, 1), a1);
        a2 = fmaf(wC, __builtin_amdgcn_cvt_f32_fp8(zC, 2), a2);
        a3 = fmaf(wC, __builtin_amdgcn_cvt_f32_fp8(zC, 3), a3);
        a0 = fmaf(wD, __builtin_amdgcn_cvt_f32_fp8(zD, 0), a0);
        a1 = fmaf(wD, __builtin_amdgcn_cvt_f32_fp8(zD, 1), a1);
        a2 = fmaf(wD, __builtin_amdgcn_cvt_f32_fp8(zD, 2), a2);
        a3 = fmaf(wD, __builtin_amdgcn_cvt_f32_fp8(zD, 3), a3);
    }
    for (; i < e; i += 4) {                 // tail: predicated quad-slot
        int ee = i + q;
        unsigned p = (ee < e) ? epk[ee] : 0u;   // w=+0 kills the lane
        unsigned z = Z1[(p & 0xFFFF) * 16 + s];
        float w = __uint_as_float(p & 0xFFFF0000u);
        a0 = fmaf(w, __builtin_amdgcn_cvt_f32_fp8(z, 0), a0);
        a1 = fmaf(w, __builtin_amdgcn_cvt_f32_fp8(z, 1), a1);
        a2 = fmaf(w, __builtin_amdgcn_cvt_f32_fp8(z, 2), a2);
        a3 = fmaf(w, __builtin_amdgcn_cvt_f32_fp8(z, 3), a3);
    }

    a0 += __shfl_xor(a0, 16); a0 += __shfl_xor(a0, 32);
    a1 += __shfl_xor(a1, 16); a1 += __shfl_xor(a1, 32);
    a2 += __shfl_xor(a2, 16); a2 += __shfl_xor(a2, 32);
    a3 += __shfl_xor(a3, 16); a3 += __shfl_xor(a3, 32);

    if (q == 0) {
        float r0 = fmaxf(a0 + bflo(y4.x), 0.0f);
        float r1 = fmaxf(a1 + bfhi(y4.x), 0.0f);
        float r2 = fmaxf(a2 + bflo(y4.y), 0.0f);
        float r3 = fmaxf(a3 + bfhi(y4.y), 0.0f);
        if (FP32OUT) {
            ((float4*)Hout)[node * 16 + s] = make_float4(r0, r1, r2, r3);
        } else {
            uint2 o;
            o.x = (unsigned)f2bf(r0) | ((unsigned)f2bf(r1) << 16);
            o.y = (unsigned)f2bf(r2) | ((unsigned)f2bf(r3) << 16);
            ((uint2*)Hout)[node * 16 + s] = o;
        }
    }
}

extern "C" void kernel_launch(void* const* d_in, const int* in_sizes, int n_in,
                              void* d_out, int out_size, void* d_ws, size_t ws_size,
                              hipStream_t stream)
{
    const float* x     = (const float*)d_in[0];
    const int*   ei    = (const int*)  d_in[1];
    const float* ew    = (const float*)d_in[2];
    const float* Wrel1 = (const float*)d_in[3];
    const float* brel1 = (const float*)d_in[4];
    const float* Wroot1= (const float*)d_in[5];
    const float* Wrel2 = (const float*)d_in[6];
    const float* brel2 = (const float*)d_in[7];
    const float* Wroot2= (const float*)d_in[8];

    float* out = (float*)d_out;                 // final output only

    const size_t ND = (size_t)NN * DD;          // 3.2e6 elements
    // ALL regions disjoint. Total ~26.3 MB (ws = 256 MiB).
    char* w = (char*)d_ws;
    unsigned char*  Z8 = (unsigned char*)w;                     //  3.20 MB
    unsigned short* Yb = (unsigned short*)(w + ND);             //  6.40 MB
    unsigned short* Hb = (unsigned short*)(w + ND * 3);         //  6.40 MB
    unsigned* epk = (unsigned*)(w + ND * 5);                    //  8.01 MB
    int* beg  = (int*)(w + ND * 5 + (size_t)NB * PAD * 4);      //  0.20 MB
    int* endo = beg + NN;                                       //  0.20 MB
    int* bsz  = endo + NN;                                      //  3 KB
    int* hist = bsz + NB;                                       //  0.61 MB
    int* offs = hist + (size_t)NC * NB;                         //  0.61 MB

    const int tb = (NN + 63) / 64;              // 782 transform blocks
    const int ab = (NN + 3) / 4;                // 12500 aggregate blocks

    // ---- fused: histogram chunks + layer-1 transform (independent) ----
    hist_t1_kernel<<<NC + tb, 256, 0, stream>>>(ei, hist, x, Wrel1, Wroot1,
                                                brel1, Z8, Yb);
    // ---- rest of the build (graph shared by both layers) ----
    colscan_kernel<<<NB, 256, 0, stream>>>(hist, offs, bsz);
    bin_kernel    <<<NC, 256, 0, stream>>>(ei, ew, offs, epk);
    sort_kernel   <<<NB, 256, 0, stream>>>(epk, bsz, beg, endo);

    // ---- layer 1 aggregate ----
    aggregate_kernel<false><<<ab, 256, 0, stream>>>(
        (const unsigned*)Z8, (const uint2*)Yb, beg, endo, epk, Hb);

    // ---- layer 2 ----
    transform2_kernel<<<tb, 256, 0, stream>>>(Hb, Wrel2, Wroot2, brel2, Z8, Yb);
    aggregate_kernel<true><<<ab, 256, 0, stream>>>(
        (const unsigned*)Z8, (const uint2*)Yb, beg, endo, epk, out);
}